// Round 2
// baseline (88.818 us; speedup 1.0000x reference)
//
#include <hip/hip_runtime.h>
#include <math.h>

// x [B=1024, S=256, E=4] fp32. One block = one batch (256 threads, 4 waves).
// R9: matrix-pipe attention, NaN-proofed.
//  - scores: S^T tile = mfma_f32_16x16x32_f16(K-frag, Q-frag, -mhat), hi/lo
//    fp16 split => (kh+kl)(qh+ql) exact product of split values (~2^-21 rel).
//  - P.V: bf16 MFMA (range!). fp16 P-split underflowed (mhat gap > 24 =>
//    all-zero P row => l=0 => 0*inf NaN, the R8 failure). bf16 subnormals
//    reach 2^-133; worst gap ~70 => p never fully underflows, l > 0 always.
//    P split Ph+Pl (RTZ via v_perm), V split Vh+Vl (RNE, phase 0).
//    Ones-column in Vh row 4 accumulates l in the same MFMA accumulator.
//  - swapped-QK: score C-frag (col=lane&15=query, row=4g+i=key) feeds the
//    PV A-frag lane-locally, zero shuffles. No __syncthreads in hot loop.
constexpr int S  = 256;
constexpr int E  = 4;
constexpr int H1 = 8;
constexpr int H2 = 4;

typedef __attribute__((ext_vector_type(8))) _Float16 half8;
typedef __attribute__((ext_vector_type(8))) short    bf16x8;
typedef __attribute__((ext_vector_type(4))) float    f32x4;
typedef __attribute__((ext_vector_type(4))) int      i32x4;

__device__ __forceinline__ float fast_tanh(float x) {
    const float z = __builtin_amdgcn_exp2f(x * 2.88539008f);  // e^(2x)
    return 1.f - 2.f * __builtin_amdgcn_rcpf(z + 1.f);        // inf-safe
}

// fp32 -> (hi fp16, lo fp16) split, hi RNE, residual captured in lo.
__device__ __forceinline__ void split16(float x, unsigned short& hi, unsigned short& lo) {
    _Float16 h = (_Float16)x;
    float r = x - (float)h;
    _Float16 l = (_Float16)r;
    hi = __builtin_bit_cast(unsigned short, h);
    lo = __builtin_bit_cast(unsigned short, l);
}

__device__ __forceinline__ unsigned short bf16_rne(float x) {
    unsigned u = __builtin_bit_cast(unsigned, x);
    u = (u + 0x7FFFu + ((u >> 16) & 1u)) >> 16;
    return (unsigned short)u;
}
__device__ __forceinline__ float bf16_as_f32(unsigned short h) {
    return __builtin_bit_cast(float, (unsigned)h << 16);
}

// pack: low16 = bf16_rtz(a), high16 = bf16_rtz(b)  (one v_perm_b32)
__device__ __forceinline__ unsigned pk_bf16(float a, float b) {
    return __builtin_amdgcn_perm(__builtin_bit_cast(unsigned, b),
                                 __builtin_bit_cast(unsigned, a), 0x07060302u);
}
__device__ __forceinline__ float hi_part(float a) {  // bf16_rtz(a) as f32
    return __builtin_bit_cast(float, __builtin_bit_cast(unsigned, a) & 0xFFFF0000u);
}

__device__ __forceinline__ half8 frag(int a, int b, int c, int d) {
    i32x4 t = {a, b, c, d};
    return __builtin_bit_cast(half8, t);
}
__device__ __forceinline__ bf16x8 bfrag(int a, int b, int c, int d) {
    i32x4 t = {a, b, c, d};
    return __builtin_bit_cast(bf16x8, t);
}
__device__ __forceinline__ f32x4 mfma_f16(half8 a, half8 b, f32x4 c) {
    return __builtin_amdgcn_mfma_f32_16x16x32_f16(a, b, c, 0, 0, 0);
}
__device__ __forceinline__ f32x4 mfma_bf16(bf16x8 a, bf16x8 b, f32x4 c) {
    return __builtin_amdgcn_mfma_f32_16x16x32_bf16(a, b, c, 0, 0, 0);
}

__global__ __launch_bounds__(256, 4) void attn_mlp_kernel(
    const float* __restrict__ x,
    const float* __restrict__ Wq, const float* __restrict__ Wk, const float* __restrict__ Wv,
    const float* __restrict__ W1, const float* __restrict__ b1,
    const float* __restrict__ W2, const float* __restrict__ b2,
    const float* __restrict__ W3, const float* __restrict__ b3,
    float* __restrict__ out)
{
    const int b    = blockIdx.x;
    const int tid  = threadIdx.x;
    const int w    = tid >> 6;
    const int lane = tid & 63;
    const int g    = lane >> 4;
    const int c15  = lane & 15;

    __shared__ i32x4 qrec[S];                         // [qh01,qh23,ql01,ql23] fp16
    __shared__ i32x4 krec[S];                         // [kh01,kh23,kl01,kl23] fp16
    __shared__ __align__(16) unsigned short vhT[16][264];  // bf16: rows 0-3 vh, 4 ones, 5-15 zero
    __shared__ __align__(16) unsigned short vlT[16][264];  // bf16: rows 0-3 vl, 4-15 zero
    __shared__ float mh_lds[S];                       // NEGATED per-row score bound
    __shared__ float accb[S][9];                      // [v0..v3, l] + pad
    __shared__ float kmax_lds[4];

    // ---- Phase 0: q/k/v for row tid; splits into LDS ----
    const float4 xr = *reinterpret_cast<const float4*>(x + ((size_t)b * S + tid) * E);
    const float xv[E] = {xr.x, xr.y, xr.z, xr.w};
    float qq = 0.f, kk = 0.f;
    {
        float q[E], k[E], v[E];
        #pragma unroll
        for (int e = 0; e < E; ++e) {
            float aq = 0.f, ak = 0.f, av = 0.f;
            #pragma unroll
            for (int i = 0; i < E; ++i) {
                aq = fmaf(xv[i], Wq[i * E + e], aq);
                ak = fmaf(xv[i], Wk[i * E + e], ak);
                av = fmaf(xv[i], Wv[i * E + e], av);
            }
            q[e] = aq * 0.72134752f;  // fold 1/sqrt(E), log2(e): exp2 domain
            k[e] = ak;
            v[e] = av;
            qq = fmaf(q[e], q[e], qq);
            kk = fmaf(ak, ak, kk);
        }
        unsigned short qh[4], ql[4], kh[4], kl[4];
        #pragma unroll
        for (int e = 0; e < E; ++e) {
            split16(q[e], qh[e], ql[e]);
            split16(k[e], kh[e], kl[e]);
        }
        qrec[tid] = (i32x4){ (int)(qh[0] | (qh[1] << 16)), (int)(qh[2] | (qh[3] << 16)),
                             (int)(ql[0] | (ql[1] << 16)), (int)(ql[2] | (ql[3] << 16)) };
        krec[tid] = (i32x4){ (int)(kh[0] | (kh[1] << 16)), (int)(kh[2] | (kh[3] << 16)),
                             (int)(kl[0] | (kl[1] << 16)), (int)(kl[2] | (kl[3] << 16)) };
        #pragma unroll
        for (int e = 0; e < E; ++e) {
            const unsigned short vh = bf16_rne(v[e]);
            const unsigned short vl = bf16_rne(v[e] - bf16_as_f32(vh));
            vhT[e][tid] = vh;
            vlT[e][tid] = vl;
        }
        vhT[4][tid] = 0x3F80;  // bf16 1.0 ones-column -> l
        #pragma unroll
        for (int r = 5; r < 16; ++r) vhT[r][tid] = 0;
        #pragma unroll
        for (int r = 4; r < 16; ++r) vlT[r][tid] = 0;

        #pragma unroll
        for (int off = 32; off > 0; off >>= 1)
            kk = fmaxf(kk, __shfl_xor(kk, off));
        if (lane == 0) kmax_lds[w] = kk;
    }
    __syncthreads();
    const float kmax2 = fmaxf(fmaxf(kmax_lds[0], kmax_lds[1]),
                              fmaxf(kmax_lds[2], kmax_lds[3]));
    mh_lds[tid] = -sqrtf(qq * kmax2);   // >= every score (exp2 domain), negated
    __syncthreads();

    // ---- hoisted per-row-tile state: wave w owns rows 64w..64w+63 ----
    half8 Bq[4];
    float negmh[4];
    f32x4 acc[4];
    #pragma unroll
    for (int rt = 0; rt < 4; ++rt) {
        const int s = 64 * w + 16 * rt + c15;     // query col for this lane
        i32x4 u = qrec[s];
        int h0 = (g == 0) ? u[0] : u[2];
        int h1 = (g == 0) ? u[1] : u[3];
        if (g >= 2) { h0 = 0; h1 = 0; }
        Bq[rt] = frag(h0, h1, h0, h1);            // g0:[qh,qh] g1:[ql,ql]
        negmh[rt] = mh_lds[s];
        acc[rt] = (f32x4){0.f, 0.f, 0.f, 0.f};
    }

    // ---- main loop: 8 chunks x 32 keys, no barriers ----
    #pragma unroll 1
    for (int ch = 0; ch < 8; ++ch) {
        const int kb = ch * 32;
        i32x4 k0 = krec[kb + c15];                // key row m=c15 (tile0)
        i32x4 k1 = krec[kb + 16 + c15];           // tile1
        if (g >= 2) { k0 = (i32x4){0,0,0,0}; k1 = (i32x4){0,0,0,0}; }
        const half8 Ak0 = __builtin_bit_cast(half8, k0);   // g0/g1: [kh,kl]
        const half8 Ak1 = __builtin_bit_cast(half8, k1);

        const int vi = kb + 4 * g;                // this lane's 4 keys per tile
        const uint2 h0 = *(const uint2*)&vhT[c15][vi];
        const uint2 h1 = *(const uint2*)&vhT[c15][vi + 16];
        const uint2 l0 = *(const uint2*)&vlT[c15][vi];
        const uint2 l1 = *(const uint2*)&vlT[c15][vi + 16];
        const bf16x8 Bvh0 = bfrag((int)h0.x, (int)h0.y, (int)h0.x, (int)h0.y); // [Vh,Vh] t0
        const bf16x8 Bvh1 = bfrag((int)h1.x, (int)h1.y, (int)h1.x, (int)h1.y); // [Vh,Vh] t1
        const bf16x8 Bvl  = bfrag((int)l0.x, (int)l0.y, (int)l1.x, (int)l1.y); // [Vl t0,Vl t1]

        #pragma unroll
        for (int rt = 0; rt < 4; ++rt) {
            const f32x4 cm = {negmh[rt], negmh[rt], negmh[rt], negmh[rt]};
            const f32x4 c0 = mfma_f16(Ak0, Bq[rt], cm);   // S^T - mhat, keys kb+4g+i
            const f32x4 c1 = mfma_f16(Ak1, Bq[rt], cm);   // keys kb+16+4g+i
            const float p0 = __builtin_amdgcn_exp2f(c0[0]);
            const float p1 = __builtin_amdgcn_exp2f(c0[1]);
            const float p2 = __builtin_amdgcn_exp2f(c0[2]);
            const float p3 = __builtin_amdgcn_exp2f(c0[3]);
            const float p4 = __builtin_amdgcn_exp2f(c1[0]);
            const float p5 = __builtin_amdgcn_exp2f(c1[1]);
            const float p6 = __builtin_amdgcn_exp2f(c1[2]);
            const float p7 = __builtin_amdgcn_exp2f(c1[3]);
            // bf16 hi/lo split of P (RTZ): hi = v_perm pack, lo = residual pack
            const unsigned hi01 = pk_bf16(p0, p1), hi23 = pk_bf16(p2, p3);
            const unsigned hi45 = pk_bf16(p4, p5), hi67 = pk_bf16(p6, p7);
            const unsigned lo01 = pk_bf16(p0 - hi_part(p0), p1 - hi_part(p1));
            const unsigned lo23 = pk_bf16(p2 - hi_part(p2), p3 - hi_part(p3));
            const unsigned lo45 = pk_bf16(p4 - hi_part(p4), p5 - hi_part(p5));
            const unsigned lo67 = pk_bf16(p6 - hi_part(p6), p7 - hi_part(p7));
            const bf16x8 A10 = bfrag((int)hi01, (int)hi23, (int)lo01, (int)lo23);
            const bf16x8 A11 = bfrag((int)hi45, (int)hi67, (int)lo45, (int)lo67);
            const bf16x8 A2  = bfrag((int)hi01, (int)hi23, (int)hi45, (int)hi67);
            acc[rt] = mfma_bf16(A10, Bvh0, acc[rt]);   // (Ph+Pl).Vh tile0 (+ l)
            acc[rt] = mfma_bf16(A11, Bvh1, acc[rt]);   // (Ph+Pl).Vh tile1 (+ l)
            acc[rt] = mfma_bf16(A2,  Bvl,  acc[rt]);   // Ph.Vl both tiles
        }
    }

    // ---- epilogue: C layout row=4g+i (query), col=c15 (v0..v3,l) ----
    #pragma unroll
    for (int rt = 0; rt < 4; ++rt) {
        if (c15 < 5) {
            const int row = 64 * w + 16 * rt + 4 * g;
            #pragma unroll
            for (int i = 0; i < 4; ++i) accb[row + i][c15] = acc[rt][i];
        }
    }
    __syncthreads();

    // ---- Phase 2: normalize + MLP, one row per thread ----
    const float inv = 1.0f / fmaxf(accb[tid][4], 1e-37f);
    float a[E];
    #pragma unroll
    for (int e = 0; e < E; ++e) a[e] = accb[tid][e] * inv;

    float h1v[H1];
    #pragma unroll
    for (int o = 0; o < H1; ++o) {
        float s = b1[o];
        #pragma unroll
        for (int i = 0; i < E; ++i) s = fmaf(a[i], W1[i * H1 + o], s);
        h1v[o] = fast_tanh(s);
    }
    float h2v[H2];
    #pragma unroll
    for (int o = 0; o < H2; ++o) {
        float s = b2[o];
        #pragma unroll
        for (int i = 0; i < H1; ++i) s = fmaf(h1v[i], W2[i * H2 + o], s);
        h2v[o] = fast_tanh(s);
    }
    float r = b3[0];
    #pragma unroll
    for (int i = 0; i < H2; ++i) r = fmaf(h2v[i], W3[i], r);

    out[(size_t)b * S + tid] = r;
}

extern "C" void kernel_launch(void* const* d_in, const int* in_sizes, int n_in,
                              void* d_out, int out_size, void* d_ws, size_t ws_size,
                              hipStream_t stream) {
    const float* x  = (const float*)d_in[0];
    const float* Wq = (const float*)d_in[1];
    const float* Wk = (const float*)d_in[2];
    const float* Wv = (const float*)d_in[3];
    const float* W1 = (const float*)d_in[4];
    const float* b1 = (const float*)d_in[5];
    const float* W2 = (const float*)d_in[6];
    const float* b2 = (const float*)d_in[7];
    const float* W3 = (const float*)d_in[8];
    const float* b3 = (const float*)d_in[9];
    float* out = (float*)d_out;

    const int B = in_sizes[0] / (S * E);   // 1024
    attn_mlp_kernel<<<dim3(B), dim3(256), 0, stream>>>(
        x, Wq, Wk, Wv, W1, b1, W2, b2, W3, b3, out);
}